// Round 6
// baseline (499.815 us; speedup 1.0000x reference)
//
#include <hip/hip_runtime.h>
#include <hip/hip_bf16.h>

// CosSim2D (K=3, same-pad, C=32 -> F=32) on MI355X.
// Round 6: ABLATION of the round-3 kernel (best so far, main ~33us).
//   V0: stage->LDS only            (REP=12)
//   V1: + xinv + K-loop (MFMA)     (REP=5)
//   V2: + epilogue math (no store) (REP=4)
//   V3: full (= round-3 kernel)    (REP=2)
//   V4: full + exp==1 fast path    (REP=2, runs last -> final output)
// Keep-alives via asm volatile defeat DCE (skill rule #17); "memory" clobber
// per rep forces real global re-loads. Per-variant dur comes from rocprof
// top-5 (each variant's dispatch > the ~40us poison fills).

#define H_ 224
#define W_ 224
#define C_ 32
#define F_ 32

#define NSTEP 18   // K = 288 = 18 * 16
#define HROWS 10
#define HCOLS 34

typedef __bf16 bf16_t;
typedef bf16_t bf16x8 __attribute__((ext_vector_type(8)));
typedef float f32x16 __attribute__((ext_vector_type(16)));

#define WFRAG_BYTES (NSTEP * 64 * 8 * 2)  // 18432 B

// ---------------- prep (6 blocks): w-norm + exponents + B-fragments ---------
__global__ __launch_bounds__(256) void cos2d_prep(
    const float* __restrict__ w, const float* __restrict__ p,
    const float* __restrict__ q, bf16_t* __restrict__ wfrag,
    float* __restrict__ winv, float* __restrict__ ef) {
  const int tid = threadIdx.x;
  if (blockIdx.x == 0) {
    __shared__ float part[8][32];
    const int f = tid & 31, kg = tid >> 5;
    float s = 0.f;
#pragma unroll
    for (int i = 0; i < 36; ++i) {
      const float v = w[(kg + 8 * i) * F_ + f];
      s += v * v;
    }
    part[kg][f] = s;
    __syncthreads();
    if (tid < 32) {
      float t = 0.f;
#pragma unroll
      for (int g = 0; g < 8; ++g) t += part[g][tid];
      const float qt = q[0] * q[0] * 0.1f;
      winv[tid] = 1.f / (sqrtf(fmaxf(t, 1e-12f)) + qt);
      ef[tid] = p[tid] * p[tid] * 0.01f;
    }
  } else {
    // B-fragment layout for mfma_f32_32x32x16_bf16:
    //   lane l holds col f = l&31, k = s2*16 + (l>>5)*8 + e  (e = 0..7).
    const int t = (blockIdx.x - 1) * 256 + tid;
    if (t < NSTEP * 64) {
      const int s2 = t >> 6, l = t & 63;
      const int ff = l & 31;
      union { bf16_t v[8]; uint4 u; } tv;
#pragma unroll
      for (int e = 0; e < 8; ++e) {
        const int kk = s2 * 16 + ((l >> 5) << 3) + e;
        tv.v[e] = (bf16_t)w[kk * F_ + ff];
      }
      *(uint4*)(wfrag + (size_t)t * 8) = tv.u;
    }
  }
}

// ---------------- ablation main ---------------------------------------------
template <int V, int REP>
__global__ __launch_bounds__(256, 5) void cos2d_abl(
    const float* __restrict__ img, const bf16_t* __restrict__ wfrag,
    const float* __restrict__ winv, const float* __restrict__ ef,
    const float* __restrict__ q, float* __restrict__ out) {
  __shared__ bf16_t xt[HROWS][HCOLS][40];
  __shared__ float ssum[HROWS][HCOLS];

  const int tid = threadIdx.x;
  const int lane = tid & 63;
  const int wv = tid >> 6;
  const int lp = lane & 31;

  const int bid = blockIdx.x;
  const int tw = bid % 7;
  const int th = (bid / 7) % 28;
  const int b  = bid / 196;
  const int h0 = th * 8, w0 = tw * 32;

  const float qt = q[0] * q[0] * 0.1f;
  const float efv = ef[lp];
  const float wnv = winv[lp];
  // wave-uniform here (all p equal); guarded so arbitrary inputs stay correct
  // (|e-1|<1e-6 -> |x^e - x| << threshold for |x|<=1e3).
  const bool allfast = __all(__builtin_fabsf(efv - 1.0f) < 1e-6f);

  for (int rep = 0; rep < REP; ++rep) {
    asm volatile("" ::: "memory");  // force real re-loads each rep
    __syncthreads();                // prior rep's readers done

    // ---- phase S: stage halo tile (round-3 pattern) ----
    for (int idx = tid; idx < HROWS * HCOLS; idx += 256) {
      const int rr = idx / HCOLS, cc = idx - rr * HCOLS;
      const int hh = h0 - 1 + rr, wc = w0 - 1 + cc;
      float s = 0.f;
      union { bf16_t v[32]; uint4 u[4]; } tv;
      if ((unsigned)hh < H_ && (unsigned)wc < W_) {
        const float4* p4 =
            (const float4*)(img + ((size_t)(b * H_ + hh) * W_ + wc) * C_);
#pragma unroll
        for (int jj = 0; jj < 8; ++jj) {
          const float4 v = p4[jj];
          s += v.x * v.x + v.y * v.y + v.z * v.z + v.w * v.w;
          tv.v[4 * jj + 0] = (bf16_t)v.x;
          tv.v[4 * jj + 1] = (bf16_t)v.y;
          tv.v[4 * jj + 2] = (bf16_t)v.z;
          tv.v[4 * jj + 3] = (bf16_t)v.w;
        }
      } else {
#pragma unroll
        for (int jj = 0; jj < 4; ++jj) tv.u[jj] = make_uint4(0u, 0u, 0u, 0u);
      }
      ssum[rr][cc] = s;
      uint4* dst = (uint4*)&xt[rr][cc][0];
#pragma unroll
      for (int jj = 0; jj < 4; ++jj) dst[jj] = tv.u[jj];
    }
    __syncthreads();
    {  // keep staged data observably live
      const float k0 = ((const float*)&xt[0][0][0])[tid];
      const float k1 = ((const float*)&ssum[0][0])[tid];
      asm volatile("" :: "v"(k0), "v"(k1));
    }
    if constexpr (V == 0) continue;

    // ---- phase X: x-norms ----
    const int mr0 = wv * 2;
    float xinv[2];
#pragma unroll
    for (int t = 0; t < 2; ++t) {
      const int mr = mr0 + t;
      const float xn2 =
          ssum[mr + 0][lp] + ssum[mr + 0][lp + 1] + ssum[mr + 0][lp + 2] +
          ssum[mr + 1][lp] + ssum[mr + 1][lp + 1] + ssum[mr + 1][lp + 2] +
          ssum[mr + 2][lp] + ssum[mr + 2][lp + 1] + ssum[mr + 2][lp + 2];
      xinv[t] = 1.f / (sqrtf(fmaxf(xn2, 1e-12f)) + qt);
    }

    // ---- phase K: MFMA K-loop ----
    f32x16 acc0, acc1;
#pragma unroll
    for (int i = 0; i < 16; ++i) { acc0[i] = 0.f; acc1[i] = 0.f; }
    const bf16x8* wf4 = (const bf16x8*)wfrag;
#pragma unroll
    for (int s2 = 0; s2 < NSTEP; ++s2) {
      const bf16x8 bf = wf4[s2 * 64 + lane];
      const int pos = s2 >> 1;
      const int dy = pos / 3, dx = pos - dy * 3;
      const int chof = (s2 & 1) * 16 + ((lane >> 5) << 3);
      const bf16x8 a0 = *(const bf16x8*)&xt[mr0 + 0 + dy][lp + dx][chof];
      const bf16x8 a1 = *(const bf16x8*)&xt[mr0 + 1 + dy][lp + dx][chof];
      acc0 = __builtin_amdgcn_mfma_f32_32x32x16_bf16(a0, bf, acc0, 0, 0, 0);
      acc1 = __builtin_amdgcn_mfma_f32_32x32x16_bf16(a1, bf, acc1, 0, 0, 0);
    }
    if constexpr (V == 1) {
#pragma unroll
      for (int i = 0; i < 16; ++i)
        asm volatile("" :: "v"(acc0[i]), "v"(acc1[i]));
      asm volatile("" :: "v"(xinv[0]), "v"(xinv[1]));
      continue;
    }

    // ---- phase E/W: epilogue (+ stores for V>=3) ----
#pragma unroll
    for (int t = 0; t < 2; ++t) {
      const f32x16& acc = t ? acc1 : acc0;
      const int obase = (b * H_ + h0 + mr0 + t) * W_ + w0;
      if (V == 4 && allfast) {
#pragma unroll
        for (int jj = 0; jj < 16; ++jj) {
          const int row = (jj & 3) + 8 * (jj >> 2) + 4 * (lane >> 5);
          const float xi = __shfl(xinv[t], row);
          const float sim = acc[jj] * xi * wnv;
          const float r = copysignf(fabsf(sim) + 1e-12f, sim);  // e == 1
          out[(size_t)(obase + row) * F_ + lp] = r;
        }
      } else {
#pragma unroll
        for (int jj = 0; jj < 16; ++jj) {
          const int row = (jj & 3) + 8 * (jj >> 2) + 4 * (lane >> 5);
          const float xi = __shfl(xinv[t], row);
          const float sim = acc[jj] * xi * wnv;
          const float ps = fabsf(sim) + 1e-12f;
          float r = exp2f(efv * __log2f(ps));
          r = copysignf(r, sim);
          if constexpr (V == 2)
            asm volatile("" :: "v"(r));
          else
            out[(size_t)(obase + row) * F_ + lp] = r;
        }
      }
    }
  }
}

// ---------------- launch ----------------------------------------------------
extern "C" void kernel_launch(void* const* d_in, const int* in_sizes, int n_in,
                              void* d_out, int out_size, void* d_ws, size_t ws_size,
                              hipStream_t stream) {
  const float* img = (const float*)d_in[0];
  const float* w   = (const float*)d_in[1];
  const float* p   = (const float*)d_in[2];
  const float* q   = (const float*)d_in[3];

  bf16_t* wfrag = (bf16_t*)d_ws;
  float*  winv  = (float*)((char*)d_ws + WFRAG_BYTES);
  float*  ef    = winv + 64;
  float*  o     = (float*)d_out;

  cos2d_prep<<<6, 256, 0, stream>>>(w, p, q, wfrag, winv, ef);
  cos2d_abl<0, 12><<<1568, 256, 0, stream>>>(img, wfrag, winv, ef, q, o);
  cos2d_abl<1, 5><<<1568, 256, 0, stream>>>(img, wfrag, winv, ef, q, o);
  cos2d_abl<2, 4><<<1568, 256, 0, stream>>>(img, wfrag, winv, ef, q, o);
  cos2d_abl<3, 2><<<1568, 256, 0, stream>>>(img, wfrag, winv, ef, q, o);
  cos2d_abl<4, 2><<<1568, 256, 0, stream>>>(img, wfrag, winv, ef, q, o);
}

// Round 7
// 34.542 us; speedup vs baseline: 14.4699x; 14.4699x over previous
//
#include <hip/hip_runtime.h>
#include <hip/hip_bf16.h>

// CosSim2D (K=3, same-pad, C=32 -> F=32) on MI355X.
// Round 7: r3 base + ablation-guided fixes.
//   Ablation (r6): S=9.5us, K~5, E~4, W~14 (of 33us total).
//   1) coalesced staging (8 lanes/pixel) -> 8x fewer L1 line-accesses.
//   2) nontemporal stores -> don't dirty L2 with 51MB of streaming output.
//   3) exp==1 fast path (guarded by runtime __all; exact for p^2/100==1).

#define H_ 224
#define W_ 224
#define C_ 32
#define F_ 32

#define NSTEP 18   // K = 288 = 18 * 16
#define HROWS 10   // staged halo rows (8 + 2)
#define HCOLS 34   // staged halo cols (32 + 2)
#define SLOTS (HROWS * HCOLS * 8)   // 2720 float4 slots

typedef __bf16 bf16_t;
typedef bf16_t bf16x8 __attribute__((ext_vector_type(8)));
typedef float f32x16 __attribute__((ext_vector_type(16)));

#define WFRAG_BYTES (NSTEP * 64 * 8 * 2)  // 18432 B

// ---------------- prep (6 blocks): w-norm + exponents + B-fragments ---------
__global__ __launch_bounds__(256) void cos2d_prep(
    const float* __restrict__ w, const float* __restrict__ p,
    const float* __restrict__ q, bf16_t* __restrict__ wfrag,
    float* __restrict__ winv, float* __restrict__ ef) {
  const int tid = threadIdx.x;
  if (blockIdx.x == 0) {
    __shared__ float part[8][32];
    const int f = tid & 31, kg = tid >> 5;
    float s = 0.f;
#pragma unroll
    for (int i = 0; i < 36; ++i) {
      const float v = w[(kg + 8 * i) * F_ + f];
      s += v * v;
    }
    part[kg][f] = s;
    __syncthreads();
    if (tid < 32) {
      float t = 0.f;
#pragma unroll
      for (int g = 0; g < 8; ++g) t += part[g][tid];
      const float qt = q[0] * q[0] * 0.1f;
      winv[tid] = 1.f / (sqrtf(fmaxf(t, 1e-12f)) + qt);
      ef[tid] = p[tid] * p[tid] * 0.01f;
    }
  } else {
    // B-fragment layout for mfma_f32_32x32x16_bf16:
    //   lane l holds col f = l&31, k = s2*16 + (l>>5)*8 + e  (e = 0..7).
    const int t = (blockIdx.x - 1) * 256 + tid;
    if (t < NSTEP * 64) {
      const int s2 = t >> 6, l = t & 63;
      const int ff = l & 31;
      union { bf16_t v[8]; uint4 u; } tv;
#pragma unroll
      for (int e = 0; e < 8; ++e) {
        const int kk = s2 * 16 + ((l >> 5) << 3) + e;
        tv.v[e] = (bf16_t)w[kk * F_ + ff];
      }
      *(uint4*)(wfrag + (size_t)t * 8) = tv.u;
    }
  }
}

// ---------------- main ------------------------------------------------------
__global__ __launch_bounds__(256, 5) void cos2d_main(
    const float* __restrict__ img, const bf16_t* __restrict__ wfrag,
    const float* __restrict__ winv, const float* __restrict__ ef,
    const float* __restrict__ q, float* __restrict__ out) {
  // pixel stride 40 bf16 = 80 B (16B-aligned); <=2-way LDS bank aliasing on
  // both the staged writes and the b128 fragment reads (free per m136).
  __shared__ bf16_t xt[HROWS][HCOLS][40];
  __shared__ float ssum[HROWS][HCOLS];

  const int tid = threadIdx.x;
  const int lane = tid & 63;
  const int wv = tid >> 6;
  const int lp = lane & 31;

  const int bid = blockIdx.x;
  const int tw = bid % 7;
  const int th = (bid / 7) % 28;
  const int b  = bid / 196;
  const int h0 = th * 8, w0 = tw * 32;

  const float qt = q[0] * q[0] * 0.1f;
  const float efv = ef[lp];     // per-filter exponent (filter = lp)
  const float wnv = winv[lp];   // per-filter 1/(||w||+qt)
  // p^2/100 == 1 for this init; guarded so arbitrary inputs stay correct.
  const bool allfast = __all(__builtin_fabsf(efv - 1.0f) < 1e-6f);

  // ---- coalesced staging: 8 lanes per pixel, lane `sub` reads float4 #sub
  // -> each wave-inst reads 8 FULL 128-B lines (was: 16 B from each of 64).
  for (int idx = tid; idx < SLOTS; idx += 256) {
    const int pp = idx >> 3, sub = idx & 7;
    const int rr = pp / HCOLS, cc = pp - rr * HCOLS;
    const int hh = h0 - 1 + rr, wc = w0 - 1 + cc;
    float4 v = make_float4(0.f, 0.f, 0.f, 0.f);
    if ((unsigned)hh < H_ && (unsigned)wc < W_)
      v = *(const float4*)(img + ((size_t)(b * H_ + hh) * W_ + wc) * C_ + sub * 4);
    float s = v.x * v.x + v.y * v.y + v.z * v.z + v.w * v.w;
    s += __shfl_xor(s, 1);
    s += __shfl_xor(s, 2);
    s += __shfl_xor(s, 4);   // 8-lane group now holds the pixel channel-sumsq
    union { bf16_t h[4]; uint2 u; } pk;
    pk.h[0] = (bf16_t)v.x; pk.h[1] = (bf16_t)v.y;
    pk.h[2] = (bf16_t)v.z; pk.h[3] = (bf16_t)v.w;
    *(uint2*)&xt[rr][cc][sub * 4] = pk.u;
    if (sub == 0) ssum[rr][cc] = s;
  }
  __syncthreads();

  const int mr0 = wv * 2;  // this wave's 2 output rows (tile-relative)

  // x_norm: 3x3 window sum of per-pixel channel sum-of-squares (fp32 exact)
  float xinv[2];
#pragma unroll
  for (int t = 0; t < 2; ++t) {
    const int mr = mr0 + t;
    const float xn2 =
        ssum[mr + 0][lp] + ssum[mr + 0][lp + 1] + ssum[mr + 0][lp + 2] +
        ssum[mr + 1][lp] + ssum[mr + 1][lp + 1] + ssum[mr + 1][lp + 2] +
        ssum[mr + 2][lp] + ssum[mr + 2][lp + 1] + ssum[mr + 2][lp + 2];
    xinv[t] = 1.f / (sqrtf(fmaxf(xn2, 1e-12f)) + qt);
  }

  f32x16 acc0, acc1;
#pragma unroll
  for (int i = 0; i < 16; ++i) { acc0[i] = 0.f; acc1[i] = 0.f; }

  // K loop: A lane l -> pixel col = l&31, k = (l>>5)*8+e (8 contig channels
  // from LDS); B streamed from wfrag (L1/L2-resident 18 KB).
  const bf16x8* wf4 = (const bf16x8*)wfrag;
#pragma unroll
  for (int s2 = 0; s2 < NSTEP; ++s2) {
    const bf16x8 bf = wf4[s2 * 64 + lane];
    const int pos = s2 >> 1;
    const int dy = pos / 3, dx = pos - dy * 3;
    const int chof = (s2 & 1) * 16 + ((lane >> 5) << 3);
    const bf16x8 a0 = *(const bf16x8*)&xt[mr0 + 0 + dy][lp + dx][chof];
    const bf16x8 a1 = *(const bf16x8*)&xt[mr0 + 1 + dy][lp + dx][chof];
    acc0 = __builtin_amdgcn_mfma_f32_32x32x16_bf16(a0, bf, acc0, 0, 0, 0);
    acc1 = __builtin_amdgcn_mfma_f32_32x32x16_bf16(a1, bf, acc1, 0, 0, 0);
  }

  // epilogue: C/D col = lane&31 (filter), row = (j&3)+8*(j>>2)+4*(lane>>5).
  // Stores are full-line coalesced; nontemporal -> don't dirty L2.
#pragma unroll
  for (int t = 0; t < 2; ++t) {
    const f32x16& acc = t ? acc1 : acc0;
    const int obase = (b * H_ + h0 + mr0 + t) * W_ + w0;
    if (allfast) {
#pragma unroll
      for (int jj = 0; jj < 16; ++jj) {
        const int row = (jj & 3) + 8 * (jj >> 2) + 4 * (lane >> 5);
        const float xi = __shfl(xinv[t], row);
        const float sim = acc[jj] * xi * wnv;
        const float r = copysignf(fabsf(sim) + 1e-12f, sim);  // |x|^1 path
        __builtin_nontemporal_store(r, &out[(size_t)(obase + row) * F_ + lp]);
      }
    } else {
#pragma unroll
      for (int jj = 0; jj < 16; ++jj) {
        const int row = (jj & 3) + 8 * (jj >> 2) + 4 * (lane >> 5);
        const float xi = __shfl(xinv[t], row);
        const float sim = acc[jj] * xi * wnv;
        const float ps = fabsf(sim) + 1e-12f;
        float r = exp2f(efv * __log2f(ps));
        r = copysignf(r, sim);
        __builtin_nontemporal_store(r, &out[(size_t)(obase + row) * F_ + lp]);
      }
    }
  }
}

// ---------------- launch ----------------------------------------------------
extern "C" void kernel_launch(void* const* d_in, const int* in_sizes, int n_in,
                              void* d_out, int out_size, void* d_ws, size_t ws_size,
                              hipStream_t stream) {
  const float* img = (const float*)d_in[0];
  const float* w   = (const float*)d_in[1];
  const float* p   = (const float*)d_in[2];
  const float* q   = (const float*)d_in[3];

  bf16_t* wfrag = (bf16_t*)d_ws;
  float*  winv  = (float*)((char*)d_ws + WFRAG_BYTES);
  float*  ef    = winv + 64;

  cos2d_prep<<<6, 256, 0, stream>>>(w, p, q, wfrag, winv, ef);
  // 8 images * 28 row-tiles * 7 col-tiles = 1568 blocks, 256 threads (4 waves)
  cos2d_main<<<1568, 256, 0, stream>>>(img, wfrag, winv, ef, q, (float*)d_out);
}